// Round 7
// baseline (164.196 us; speedup 1.0000x reference)
//
#include <hip/hip_runtime.h>
#include <hip/hip_bf16.h>

typedef __bf16 bf16;
typedef __bf16 bf16x4 __attribute__((ext_vector_type(4)));
typedef __bf16 bf16x8 __attribute__((ext_vector_type(8)));
typedef float floatx4 __attribute__((ext_vector_type(4)));

#define D_MODEL 512
#define NHEAD 8
#define HD 64
#define NB 2
#define NN 2048
#define BH (NB*NHEAD)
#define LOG2E 1.4426950408889634f

__device__ __forceinline__ float exp2_fast(float x) {
    float r;
    asm("v_exp_f32 %0, %1" : "=v"(r) : "v"(x));
    return r;
}

template<typename MT> struct MaskVec;
template<> struct MaskVec<bf16> {
    using V = bf16x4;
    static __device__ __forceinline__ float4 tof4(V v) {   // pre-scaled by LOG2E at conv
        return make_float4((float)v[0], (float)v[1], (float)v[2], (float)v[3]);
    }
};
template<> struct MaskVec<float> {
    using V = float4;
    static __device__ __forceinline__ float4 tof4(V v) {
        return make_float4(v.x*LOG2E, v.y*LOG2E, v.z*LOG2E, v.w*LOG2E);
    }
};

// ---------------- kernel 0: conversions + coordproj ----------------
__global__ __launch_bounds__(256) void convxw(const float* __restrict__ x,
                                              const float* __restrict__ w,
                                              bf16* __restrict__ xb,
                                              bf16* __restrict__ wb,
                                              const float* __restrict__ coords,
                                              const float* __restrict__ rw,
                                              float* __restrict__ cp,
                                              const float* __restrict__ maskf,
                                              bf16* __restrict__ mb) {
    int blk = blockIdx.x;
    if (blk < 2816) {
        int idx = blk * 256 + threadIdx.x;
        const float* src; bf16* dst; int i4;
        if (idx < 524288) { src = x; dst = xb; i4 = idx; }
        else              { src = w; dst = wb; i4 = idx - 524288; }
        float4 v = *(const float4*)(src + (size_t)i4*4);
        bf16x4 o; o[0] = (bf16)v.x; o[1] = (bf16)v.y; o[2] = (bf16)v.z; o[3] = (bf16)v.w;
        *(bf16x4*)(dst + (size_t)i4*4) = o;
    } else if (blk < 2832) {
        int idx = (blk - 2816) * 256 + threadIdx.x;   // (b,n)
        int b = idx >> 11, n = idx & 2047;
        float c0 = coords[idx*3 + 0];
        float c1 = coords[idx*3 + 1];
        float c2 = coords[idx*3 + 2];
        for (int h = 0; h < NHEAD; h++) {
            float v = c0*rw[h*3+0] + c1*rw[h*3+1] + c2*rw[h*3+2];
            cp[(size_t)(b*NHEAD + h)*NN + n] = v * LOG2E;
        }
    } else {
        int i4 = (blk - 2832) * 256 + threadIdx.x;    // 1048576 float4s
        float4 v = *(const float4*)(maskf + (size_t)i4*4);
        bf16x4 o;
        o[0] = (bf16)(v.x * LOG2E); o[1] = (bf16)(v.y * LOG2E);
        o[2] = (bf16)(v.z * LOG2E); o[3] = (bf16)(v.w * LOG2E);
        *(bf16x4*)(mb + (size_t)i4*4) = o;
    }
}

// ---------------- kernel 2: QKV GEMM, C^T = W*X^T, 128f x 128m tiles ----------------
// 384 blocks, 256 thr / 4 waves; wave owns 32 rows x 128 features: 32 MFMA/k-iter.
__global__ __launch_bounds__(256) void qkv_gemm(const bf16* __restrict__ xb,
                                                const bf16* __restrict__ wb,
                                                const float* __restrict__ bias,
                                                bf16* __restrict__ qb,
                                                bf16* __restrict__ kb,
                                                bf16* __restrict__ vtb) {
    __shared__ bf16 smem[128*72 + 128*72];
    bf16 (*Ws)[72] = (bf16(*)[72])smem;
    bf16 (*Xs)[72] = (bf16(*)[72])(smem + 128*72);
    int t = threadIdx.x;
    int w = t >> 6, lane = t & 63, quad = lane >> 4, l15 = lane & 15;
    int blk = blockIdx.x;
    int bfb = blk % 12, bm = blk / 12;
    int f0 = bfb * 128, m0 = bm * 128;

    floatx4 acc[8][2] = {};
    int srow = t >> 1, scol = (t & 1) * 32;

    const bf16* wsrc = wb + (size_t)(f0 + srow)*D_MODEL + scol;
    const bf16* xsrc = xb + (size_t)(m0 + srow)*D_MODEL + scol;

    bf16x8 wr[4], xr[4];
    for (int c = 0; c < 4; c++) {
        wr[c] = *(const bf16x8*)(wsrc + c*8);
        xr[c] = *(const bf16x8*)(xsrc + c*8);
    }

    for (int k0 = 0; k0 < D_MODEL; k0 += 64) {
        __syncthreads();
        for (int c = 0; c < 4; c++) {
            *(bf16x8*)&Ws[srow][scol + c*8] = wr[c];
            *(bf16x8*)&Xs[srow][scol + c*8] = xr[c];
        }
        __syncthreads();
        if (k0 + 64 < D_MODEL) {
            int kn = k0 + 64;
            for (int c = 0; c < 4; c++) {
                wr[c] = *(const bf16x8*)(wsrc + kn + c*8);
                xr[c] = *(const bf16x8*)(xsrc + kn + c*8);
            }
        }
        for (int kf = 0; kf < 2; kf++) {
            bf16x8 af[8], bx[2];
            for (int fi = 0; fi < 8; fi++)
                af[fi] = *(const bf16x8*)&Ws[fi*16 + l15][kf*32 + quad*8];
            for (int mj = 0; mj < 2; mj++)
                bx[mj] = *(const bf16x8*)&Xs[w*32 + mj*16 + l15][kf*32 + quad*8];
            for (int fi = 0; fi < 8; fi++)
                for (int mj = 0; mj < 2; mj++)
                    acc[fi][mj] = __builtin_amdgcn_mfma_f32_16x16x32_bf16(af[fi], bx[mj], acc[fi][mj], 0, 0, 0);
        }
    }

    int mat = f0 >> 9;                 // uniform per block (128 | 512)
    int h0 = (f0 >> 6) & 7;
    int b = m0 >> 11;
    int nb = m0 & 2047;
    float4 bs4[8];
    for (int fi = 0; fi < 8; fi++)
        bs4[fi] = *(const float4*)(bias + f0 + fi*16 + quad*4);

    if (mat < 2) {
        bf16* dst = (mat == 0) ? qb : kb;
        float sc = (mat == 0) ? (0.125f * LOG2E) : 1.0f;
        for (int fi = 0; fi < 8; fi++) {
            int h = h0 + (fi >> 2);
            int d = (fi & 3)*16 + quad*4;
            size_t bho = (size_t)(b*NHEAD + h);
            for (int mj = 0; mj < 2; mj++) {
                int n = nb + w*32 + mj*16 + l15;
                bf16x4 pv;
                pv[0] = (bf16)((acc[fi][mj][0] + bs4[fi].x) * sc);
                pv[1] = (bf16)((acc[fi][mj][1] + bs4[fi].y) * sc);
                pv[2] = (bf16)((acc[fi][mj][2] + bs4[fi].z) * sc);
                pv[3] = (bf16)((acc[fi][mj][3] + bs4[fi].w) * sc);
                *(bf16x4*)(dst + (bho*NN + n)*HD + d) = pv;
            }
        }
    } else {
        __syncthreads();
        bf16* Vt = smem;                       // [128][136] = 34816B
        for (int fi = 0; fi < 8; fi++) {
            int dl = fi*16 + quad*4;
            for (int mj = 0; mj < 2; mj++) {
                int mlc = w*32 + mj*16 + l15;
                Vt[(dl+0)*136 + mlc] = (bf16)(acc[fi][mj][0] + bs4[fi].x);
                Vt[(dl+1)*136 + mlc] = (bf16)(acc[fi][mj][1] + bs4[fi].y);
                Vt[(dl+2)*136 + mlc] = (bf16)(acc[fi][mj][2] + bs4[fi].z);
                Vt[(dl+3)*136 + mlc] = (bf16)(acc[fi][mj][3] + bs4[fi].w);
            }
        }
        __syncthreads();
        int dl = t >> 1, mc = (t & 1) * 64;    // 128 d-rows, 2 chunks of 64
        int h = h0 + (dl >> 6), d = dl & 63;
        bf16* gdst = vtb + ((size_t)(b*NHEAD + h)*HD + d)*NN + nb + mc;
        for (int c = 0; c < 8; c++)
            *(bf16x8*)(gdst + c*8) = *(const bf16x8*)&Vt[dl*136 + mc + c*8];
    }
}

// ---------------- kernel 3a: flash attention, 8 waves, LDS double-buffer ----------------
// grid = 16 bh * 8 qt(256 rows) * KSPLIT. 512 thr; wave owns 32 q-rows (2 subtiles of 16).
// One barrier per key-tile; K/V staged via registers into alternating LDS buffers.
template<int KSPLIT, typename MT>
__global__ __launch_bounds__(512, 4) void attn_w8(const bf16* __restrict__ qb,
                                                  const bf16* __restrict__ kb,
                                                  const bf16* __restrict__ vtb,
                                                  const MT* __restrict__ maskb,
                                                  const float* __restrict__ cp,
                                                  float* __restrict__ op,
                                                  float* __restrict__ ml,
                                                  float* __restrict__ out) {
    constexpr int NKEYS = NN / KSPLIT;
    constexpr int NTILES = NKEYS / 64;
    using MV = typename MaskVec<MT>::V;
    __shared__ bf16 Ks[2][64][72];
    __shared__ bf16 Vts[2][64][72];
    __shared__ bf16 Ps[256][72];
    __shared__ float Cs[NKEYS];
    int t = threadIdx.x;
    int w = t >> 6, lane = t & 63;
    int quad = lane >> 4, l15 = lane & 15;
    int blk = blockIdx.x;
    int bh = blk & 15;
    int rest = blk >> 4;
    int qt = rest & 7, kp = rest >> 3;
    int q0 = qt * 256;
    int kbase = kp * NKEYS;
    size_t bhoff = (size_t)bh * (NN * HD);

    bf16x8 aq[2][2];
    for (int sub = 0; sub < 2; sub++) {
        const bf16* qp = qb + bhoff + (size_t)(q0 + sub*128 + w*16 + l15)*HD + quad*8;
        aq[sub][0] = *(const bf16x8*)(qp);
        aq[sub][1] = *(const bf16x8*)(qp + 32);
    }

    float m_i[2] = {-1e30f, -1e30f}, l_i[2] = {0.f, 0.f};
    floatx4 o[2][4] = {};
    int qrow0 = q0 + w*16 + l15;
    const MT* mrow0 = maskb + (size_t)qrow0 * NN;
    const MT* mrow1 = mrow0 + (size_t)128 * NN;
    const float* cpb = cp + (size_t)bh * NN;
    int srow = t >> 3, scol = (t & 7) * 8;    // 512 thr: one bf16x8 per array

    for (int i = t; i < NKEYS; i += 512) Cs[i] = cpb[kbase + i];

    // prefetch tile 0 into registers
    bf16x8 kr, vr;
    MV mm[2][4];
    {
        kr = *(const bf16x8*)(kb + bhoff + (size_t)(kbase + srow)*HD + scol);
        vr = *(const bf16x8*)(vtb + bhoff + (size_t)srow*NN + kbase + scol);
        for (int j = 0; j < 4; j++) {
            mm[0][j] = *(const MV*)(mrow0 + kbase + j*16 + quad*4);
            mm[1][j] = *(const MV*)(mrow1 + kbase + j*16 + quad*4);
        }
    }

    int bsel = 0;
    for (int kt = 0; kt < NTILES; kt++) {
        // stage current tile into buffer bsel
        *(bf16x8*)&Ks[bsel][srow][scol]  = kr;
        *(bf16x8*)&Vts[bsel][srow][scol] = vr;
        // issue next-tile K/V global loads (waitcnt lands at next iteration's staging)
        bool more = (kt + 1 < NTILES);
        if (more) {
            int kn = kbase + (kt+1)*64;
            kr = *(const bf16x8*)(kb + bhoff + (size_t)(kn + srow)*HD + scol);
            vr = *(const bf16x8*)(vtb + bhoff + (size_t)srow*NN + kn + scol);
        }
        __syncthreads();

        // S init = mask*log2e - cp from current mm
        floatx4 s[2][4];
        int kloc = kt * 64;
        for (int sub = 0; sub < 2; sub++)
            for (int j = 0; j < 4; j++) {
                float4 mf = MaskVec<MT>::tof4(mm[sub][j]);
                float4 cv = *(const float4*)&Cs[kloc + j*16 + quad*4];
                s[sub][j][0] = mf.x - cv.x;
                s[sub][j][1] = mf.y - cv.y;
                s[sub][j][2] = mf.z - cv.z;
                s[sub][j][3] = mf.w - cv.w;
            }
        // prefetch next-tile mask
        if (more) {
            int kn = kbase + (kt+1)*64;
            for (int j = 0; j < 4; j++) {
                mm[0][j] = *(const MV*)(mrow0 + kn + j*16 + quad*4);
                mm[1][j] = *(const MV*)(mrow1 + kn + j*16 + quad*4);
            }
        }

        // S^T = K*Q'^T: K-frags reused across both q-subtiles
        for (int j = 0; j < 4; j++) {
            bf16x8 ka0 = *(const bf16x8*)&Ks[bsel][j*16 + l15][quad*8];
            bf16x8 ka1 = *(const bf16x8*)&Ks[bsel][j*16 + l15][32 + quad*8];
            s[0][j] = __builtin_amdgcn_mfma_f32_16x16x32_bf16(ka0, aq[0][0], s[0][j], 0, 0, 0);
            s[1][j] = __builtin_amdgcn_mfma_f32_16x16x32_bf16(ka0, aq[1][0], s[1][j], 0, 0, 0);
            s[0][j] = __builtin_amdgcn_mfma_f32_16x16x32_bf16(ka1, aq[0][1], s[0][j], 0, 0, 0);
            s[1][j] = __builtin_amdgcn_mfma_f32_16x16x32_bf16(ka1, aq[1][1], s[1][j], 0, 0, 0);
        }

        // softmax (base 2), two independent chains
        for (int sub = 0; sub < 2; sub++) {
            float mx = s[sub][0][0];
            for (int j = 0; j < 4; j++)
                for (int r = 0; r < 4; r++) mx = fmaxf(mx, s[sub][j][r]);
            mx = fmaxf(mx, __shfl_xor(mx, 16));
            mx = fmaxf(mx, __shfl_xor(mx, 32));
            float mnew = fmaxf(m_i[sub], mx);
            float al = exp2_fast(m_i[sub] - mnew);
            float rs = 0.f;
            for (int j = 0; j < 4; j++)
                for (int r = 0; r < 4; r++) {
                    float p = exp2_fast(s[sub][j][r] - mnew);
                    s[sub][j][r] = p;
                    rs += p;
                }
            rs += __shfl_xor(rs, 16);
            rs += __shfl_xor(rs, 32);
            l_i[sub] = l_i[sub] * al + rs;
            m_i[sub] = mnew;
            for (int dj = 0; dj < 4; dj++)
                for (int r = 0; r < 4; r++) o[sub][dj][r] *= al;
            for (int j = 0; j < 4; j++) {
                bf16x4 pv;
                pv[0] = (bf16)s[sub][j][0]; pv[1] = (bf16)s[sub][j][1];
                pv[2] = (bf16)s[sub][j][2]; pv[3] = (bf16)s[sub][j][3];
                *(bf16x4*)&Ps[sub*128 + w*16 + l15][j*16 + quad*4] = pv;
            }
        }

        // O^T += V^T * P^T: V-frags reused across both q-subtiles
        for (int kf2 = 0; kf2 < 2; kf2++) {
            bf16x8 ap0 = *(const bf16x8*)&Ps[w*16 + l15][kf2*32 + quad*8];
            bf16x8 ap1 = *(const bf16x8*)&Ps[128 + w*16 + l15][kf2*32 + quad*8];
            for (int dj = 0; dj < 4; dj++) {
                bf16x8 bv = *(const bf16x8*)&Vts[bsel][dj*16 + l15][kf2*32 + quad*8];
                o[0][dj] = __builtin_amdgcn_mfma_f32_16x16x32_bf16(bv, ap0, o[0][dj], 0, 0, 0);
                o[1][dj] = __builtin_amdgcn_mfma_f32_16x16x32_bf16(bv, ap1, o[1][dj], 0, 0, 0);
            }
        }
        bsel ^= 1;
    }

    int b = bh >> 3, h = bh & 7;
    for (int sub = 0; sub < 2; sub++) {
        int qr = q0 + sub*128 + w*16 + l15;
        if (KSPLIT == 1) {
            float inv = 1.0f / l_i[sub];
            for (int dj = 0; dj < 4; dj++) {
                floatx4 res;
                for (int r = 0; r < 4; r++) res[r] = o[sub][dj][r] * inv;
                *(floatx4*)(out + ((size_t)(b*NN + qr))*D_MODEL + h*HD + dj*16 + quad*4) = res;
            }
        } else {
            size_t pbase = (size_t)kp * BH * NN;
            float* dst = op + (pbase + (size_t)bh*NN + qr)*HD + quad*4;
            for (int dj = 0; dj < 4; dj++)
                *(floatx4*)(dst + dj*16) = o[sub][dj];
            if (quad == 0) {
                float2 v; v.x = m_i[sub]; v.y = l_i[sub];
                *(float2*)(ml + (pbase + (size_t)bh*NN + qr)*2) = v;
            }
        }
    }
}

// ---------------- kernel 3b: fallback 256-thread attention (R6) ----------------
template<int KSPLIT, typename MT>
__global__ __launch_bounds__(256, 4) void attn_t(const bf16* __restrict__ qb,
                                                 const bf16* __restrict__ kb,
                                                 const bf16* __restrict__ vtb,
                                                 const MT* __restrict__ maskb,
                                                 const float* __restrict__ cp,
                                                 float* __restrict__ op,
                                                 float* __restrict__ ml,
                                                 float* __restrict__ out) {
    constexpr int NKEYS = NN / KSPLIT;
    constexpr int NTILES = NKEYS / 64;
    using MV = typename MaskVec<MT>::V;
    __shared__ bf16 Ks[64][72];
    __shared__ bf16 Vts[64][72];
    __shared__ bf16 Ps[128][72];
    __shared__ float Cs[NKEYS];
    int t = threadIdx.x;
    int w = t >> 6, lane = t & 63;
    int quad = lane >> 4, l15 = lane & 15;
    int blk = blockIdx.x;
    int bh = blk & 15;
    int rest = blk >> 4;
    int qt = rest & 15, kp = rest >> 4;
    int q0 = qt * 128;
    int kbase = kp * NKEYS;
    size_t bhoff = (size_t)bh * (NN * HD);

    bf16x8 aq[2][2];
    for (int sub = 0; sub < 2; sub++) {
        const bf16* qp = qb + bhoff + (size_t)(q0 + sub*64 + w*16 + l15)*HD + quad*8;
        aq[sub][0] = *(const bf16x8*)(qp);
        aq[sub][1] = *(const bf16x8*)(qp + 32);
    }

    float m_i[2] = {-1e30f, -1e30f}, l_i[2] = {0.f, 0.f};
    floatx4 o[2][4] = {};
    int qrow0 = q0 + w*16 + l15;
    const MT* mrow0 = maskb + (size_t)qrow0 * NN;
    const MT* mrow1 = mrow0 + (size_t)64 * NN;
    const float* cpb = cp + (size_t)bh * NN;
    int srow = t >> 2, scol = (t & 3) * 16;

    for (int i = t; i < NKEYS; i += 256) Cs[i] = cpb[kbase + i];

    bf16x8 kr0, kr1, vr0, vr1;
    MV mm[2][4];
    {
        const bf16* ks = kb + bhoff + (size_t)(kbase + srow)*HD + scol;
        kr0 = *(const bf16x8*)ks; kr1 = *(const bf16x8*)(ks + 8);
        const bf16* vs = vtb + bhoff + (size_t)srow*NN + kbase + scol;
        vr0 = *(const bf16x8*)vs; vr1 = *(const bf16x8*)(vs + 8);
        for (int j = 0; j < 4; j++) {
            mm[0][j] = *(const MV*)(mrow0 + kbase + j*16 + quad*4);
            mm[1][j] = *(const MV*)(mrow1 + kbase + j*16 + quad*4);
        }
    }

    for (int kt = 0; kt < NTILES; kt++) {
        __syncthreads();
        *(bf16x8*)&Ks[srow][scol]      = kr0;
        *(bf16x8*)&Ks[srow][scol + 8]  = kr1;
        *(bf16x8*)&Vts[srow][scol]     = vr0;
        *(bf16x8*)&Vts[srow][scol + 8] = vr1;
        __syncthreads();

        floatx4 s[2][4];
        int kloc = kt * 64;
        for (int sub = 0; sub < 2; sub++)
            for (int j = 0; j < 4; j++) {
                float4 mf = MaskVec<MT>::tof4(mm[sub][j]);
                float4 cv = *(const float4*)&Cs[kloc + j*16 + quad*4];
                s[sub][j][0] = mf.x - cv.x;
                s[sub][j][1] = mf.y - cv.y;
                s[sub][j][2] = mf.z - cv.z;
                s[sub][j][3] = mf.w - cv.w;
            }

        bool more = (kt + 1 < NTILES);
        if (more) {
            int kn = kbase + (kt+1)*64;
            const bf16* ks = kb + bhoff + (size_t)(kn + srow)*HD + scol;
            kr0 = *(const bf16x8*)ks; kr1 = *(const bf16x8*)(ks + 8);
            const bf16* vs = vtb + bhoff + (size_t)srow*NN + kn + scol;
            vr0 = *(const bf16x8*)vs; vr1 = *(const bf16x8*)(vs + 8);
            for (int j = 0; j < 4; j++) {
                mm[0][j] = *(const MV*)(mrow0 + kn + j*16 + quad*4);
                mm[1][j] = *(const MV*)(mrow1 + kn + j*16 + quad*4);
            }
        }

        for (int j = 0; j < 4; j++) {
            bf16x8 ka0 = *(const bf16x8*)&Ks[j*16 + l15][quad*8];
            bf16x8 ka1 = *(const bf16x8*)&Ks[j*16 + l15][32 + quad*8];
            s[0][j] = __builtin_amdgcn_mfma_f32_16x16x32_bf16(ka0, aq[0][0], s[0][j], 0, 0, 0);
            s[1][j] = __builtin_amdgcn_mfma_f32_16x16x32_bf16(ka0, aq[1][0], s[1][j], 0, 0, 0);
            s[0][j] = __builtin_amdgcn_mfma_f32_16x16x32_bf16(ka1, aq[0][1], s[0][j], 0, 0, 0);
            s[1][j] = __builtin_amdgcn_mfma_f32_16x16x32_bf16(ka1, aq[1][1], s[1][j], 0, 0, 0);
        }

        for (int sub = 0; sub < 2; sub++) {
            float mx = s[sub][0][0];
            for (int j = 0; j < 4; j++)
                for (int r = 0; r < 4; r++) mx = fmaxf(mx, s[sub][j][r]);
            mx = fmaxf(mx, __shfl_xor(mx, 16));
            mx = fmaxf(mx, __shfl_xor(mx, 32));
            float mnew = fmaxf(m_i[sub], mx);
            float al = exp2_fast(m_i[sub] - mnew);
            float rs = 0.f;
            for (int j = 0; j < 4; j++)
                for (int r = 0; r < 4; r++) {
                    float p = exp2_fast(s[sub][j][r] - mnew);
                    s[sub][j][r] = p;
                    rs += p;
                }
            rs += __shfl_xor(rs, 16);
            rs += __shfl_xor(rs, 32);
            l_i[sub] = l_i[sub] * al + rs;
            m_i[sub] = mnew;
            for (int dj = 0; dj < 4; dj++)
                for (int r = 0; r < 4; r++) o[sub][dj][r] *= al;
            for (int j = 0; j < 4; j++) {
                bf16x4 pv;
                pv[0] = (bf16)s[sub][j][0]; pv[1] = (bf16)s[sub][j][1];
                pv[2] = (bf16)s[sub][j][2]; pv[3] = (bf16)s[sub][j][3];
                *(bf16x4*)&Ps[sub*64 + w*16 + l15][j*16 + quad*4] = pv;
            }
        }

        for (int kf2 = 0; kf2 < 2; kf2++) {
            bf16x8 ap0 = *(const bf16x8*)&Ps[w*16 + l15][kf2*32 + quad*8];
            bf16x8 ap1 = *(const bf16x8*)&Ps[64 + w*16 + l15][kf2*32 + quad*8];
            for (int dj = 0; dj < 4; dj++) {
                bf16x8 bv = *(const bf16x8*)&Vts[dj*16 + l15][kf2*32 + quad*8];
                o[0][dj] = __builtin_amdgcn_mfma_f32_16x16x32_bf16(bv, ap0, o[0][dj], 0, 0, 0);
                o[1][dj] = __builtin_amdgcn_mfma_f32_16x16x32_bf16(bv, ap1, o[1][dj], 0, 0, 0);
            }
        }
    }

    int b = bh >> 3, h = bh & 7;
    for (int sub = 0; sub < 2; sub++) {
        int qr = q0 + sub*64 + w*16 + l15;
        if (KSPLIT == 1) {
            float inv = 1.0f / l_i[sub];
            for (int dj = 0; dj < 4; dj++) {
                floatx4 res;
                for (int r = 0; r < 4; r++) res[r] = o[sub][dj][r] * inv;
                *(floatx4*)(out + ((size_t)(b*NN + qr))*D_MODEL + h*HD + dj*16 + quad*4) = res;
            }
        } else {
            size_t pbase = (size_t)kp * BH * NN;
            float* dst = op + (pbase + (size_t)bh*NN + qr)*HD + quad*4;
            for (int dj = 0; dj < 4; dj++)
                *(floatx4*)(dst + dj*16) = o[sub][dj];
            if (quad == 0) {
                float2 v; v.x = m_i[sub]; v.y = l_i[sub];
                *(float2*)(ml + (pbase + (size_t)bh*NN + qr)*2) = v;
            }
        }
    }
}

// ---------------- kernel 4: combine ksplit partials (m in log2 domain) ----------------
__global__ __launch_bounds__(256) void combineN(const float* __restrict__ op,
                                                const float* __restrict__ ml,
                                                float* __restrict__ out,
                                                int ksplit) {
    int idx = blockIdx.x * 256 + threadIdx.x;    // 32768 rows * 16 chunks
    int row = idx >> 4, c4 = (idx & 15) * 4;
    float mstar = -1e30f;
    for (int kp = 0; kp < ksplit; kp++)
        mstar = fmaxf(mstar, ml[((size_t)kp*BH*NN + row)*2]);
    float denom = 0.f;
    float ax = 0.f, ay = 0.f, az = 0.f, aw = 0.f;
    for (int kp = 0; kp < ksplit; kp++) {
        float2 m2 = *(const float2*)(ml + ((size_t)kp*BH*NN + row)*2);
        float wgt = exp2_fast(m2.x - mstar);
        denom += wgt * m2.y;
        float4 ov = *(const float4*)(op + ((size_t)kp*BH*NN + row)*HD + c4);
        ax += wgt*ov.x; ay += wgt*ov.y; az += wgt*ov.z; aw += wgt*ov.w;
    }
    float inv = 1.0f / denom;
    int bh = row >> 11, q = row & 2047;
    int b = bh >> 3, h = bh & 7;
    float4 res; res.x = ax*inv; res.y = ay*inv; res.z = az*inv; res.w = aw*inv;
    *(float4*)(out + ((size_t)(b*NN + q))*D_MODEL + h*HD + c4) = res;
}

extern "C" void kernel_launch(void* const* d_in, const int* in_sizes, int n_in,
                              void* d_out, int out_size, void* d_ws, size_t ws_size,
                              hipStream_t stream) {
    const float* x      = (const float*)d_in[0];
    const float* coords = (const float*)d_in[1];
    const float* amask  = (const float*)d_in[2];
    const float* qkv_w  = (const float*)d_in[3];
    const float* qkv_b  = (const float*)d_in[4];
    const float* rw     = (const float*)d_in[5];
    float* out = (float*)d_out;

    char* ws = (char*)d_ws;
    float* cp  = (float*)(ws + 0);          // 131072
    bf16*  xb  = (bf16*) (ws + 131072);     // 4 MB
    bf16*  wb  = (bf16*) (ws + 4325376);    // 1.5 MB
    bf16*  qb  = (bf16*) (ws + 5898240);    // 4 MB
    bf16*  kb  = (bf16*) (ws + 10092544);   // 4 MB
    bf16*  vtb = (bf16*) (ws + 14286848);   // 4 MB   -> end 18481152
    bf16*  mb  = (bf16*) (ws + 18481152);   // 8 MB when mask-bf16 enabled

    int split; bool mbf;
    if      (ws_size >= 60948480u) { split = 4; mbf = true;  }
    else if (ws_size >= 53084160u) { split = 4; mbf = false; }
    else if (ws_size >= 44171264u) { split = 2; mbf = true;  }
    else if (ws_size >= 35782656u) { split = 2; mbf = false; }
    else                           { split = 1; mbf = false; }

    size_t opoff = mbf ? 26869760u : 18481152u;
    float* op = (float*)(ws + opoff);
    float* ml = (float*)(ws + opoff + (size_t)split*8388608);

    convxw<<<dim3(mbf ? 6928 : 2832), dim3(256), 0, stream>>>(
        x, qkv_w, xb, wb, coords, rw, cp, amask, mb);
    qkv_gemm<<<dim3(384), dim3(256), 0, stream>>>(xb, wb, qkv_b, qb, kb, vtb);

    if (split == 4) {
        if (mbf) attn_w8<4, bf16 ><<<dim3(512), dim3(512), 0, stream>>>(qb, kb, vtb, mb,    cp, op, ml, out);
        else     attn_w8<4, float><<<dim3(512), dim3(512), 0, stream>>>(qb, kb, vtb, amask, cp, op, ml, out);
    } else if (split == 2) {
        if (mbf) attn_t<2, bf16 ><<<dim3(512),  dim3(256), 0, stream>>>(qb, kb, vtb, mb,    cp, op, ml, out);
        else     attn_t<2, float><<<dim3(512),  dim3(256), 0, stream>>>(qb, kb, vtb, amask, cp, op, ml, out);
    } else {
        attn_t<1, float><<<dim3(256), dim3(256), 0, stream>>>(qb, kb, vtb, amask, cp, op, ml, out);
    }
    if (split > 1)
        combineN<<<dim3(2048), dim3(256), 0, stream>>>(op, ml, out, split);
}